// Round 2
// baseline (3660.843 us; speedup 1.0000x reference)
//
#include <hip/hip_runtime.h>

#define C1c 4.0e-4f
#define C2c 3.6e-3f

typedef float f4 __attribute__((ext_vector_type(4), aligned(4)));

__global__ void zero_ws(double* ws) {
  if (threadIdx.x < 2) ws[threadIdx.x] = 0.0;
}

__device__ __forceinline__ float rfl(float v) {
  return __builtin_bit_cast(float,
      __builtin_amdgcn_readfirstlane(__builtin_bit_cast(int, v)));
}

// Loads rows (rv), (rv)+1 of both images into xl/yl (12-element windows,
// cols c0-5 .. c0+6). Border waves (bw) take an exact scalar clamped+masked
// path; interior waves take 3x float4 per signal per row. OOB rows -> zeros.
#define LOADROWS(rv)                                                         \
  do {                                                                       \
    _Pragma("unroll") for (int rr = 0; rr < 2; ++rr) {                       \
      const int rq = (rv) + rr;                                              \
      if ((unsigned)rq < 512u) {                                             \
        const float* __restrict__ xr = xi + ((size_t)rq << 9);               \
        const float* __restrict__ yr = yi + ((size_t)rq << 9);               \
        if (bw) {                                                            \
          _Pragma("unroll") for (int i = 0; i < 11; ++i) {                   \
            int col = c0 - 5 + i;                                            \
            unsigned ok = (unsigned)col < 512u;                              \
            int cc = ok ? col : 0;                                           \
            float xv = xr[cc], yv = yr[cc];                                  \
            xl[rr][i] = ok ? xv : 0.f;                                       \
            yl[rr][i] = ok ? yv : 0.f;                                       \
          }                                                                  \
          xl[rr][11] = 0.f; yl[rr][11] = 0.f;                                \
        } else {                                                             \
          _Pragma("unroll") for (int j = 0; j < 3; ++j) {                    \
            f4 xv = *(const f4*)(xr + (c0 - 5) + 4 * j);                     \
            f4 yv = *(const f4*)(yr + (c0 - 5) + 4 * j);                     \
            _Pragma("unroll") for (int e = 0; e < 4; ++e) {                  \
              xl[rr][4 * j + e] = xv[e];                                     \
              yl[rr][4 * j + e] = yv[e];                                     \
            }                                                                \
          }                                                                  \
        }                                                                    \
      } else {                                                               \
        _Pragma("unroll") for (int i = 0; i < 12; ++i) {                     \
          xl[rr][i] = 0.f; yl[rr][i] = 0.f;                                  \
        }                                                                    \
      }                                                                      \
    }                                                                        \
  } while (0)

// One pipeline step at compile-time phase P (0..5):
//  1) fused MSE on current rows, 2) hconv current rows -> hist slots 2P,2P+1
//  3) prefetch next row pair, 4) vconv + SSIM formula (hidden under prefetch)
#define ITER(P, DO_OUT)                                                      \
  do {                                                                       \
    _Pragma("unroll") for (int rr = 0; rr < 2; ++rr) {                       \
      if ((unsigned)(ri + rr - r0) < 64u) {                                  \
        float dx = xl[rr][5] - yl[rr][5];                                    \
        mse_acc = fmaf(dx, dx, mse_acc);                                     \
      }                                                                      \
    }                                                                        \
    _Pragma("unroll") for (int rr = 0; rr < 2; ++rr) {                       \
      float xv = xl[rr][0], yv = yl[rr][0];                                  \
      float tx = w[0] * xv, ty = w[0] * yv;                                  \
      float h0 = tx, h1 = ty, h2 = tx * xv, h3 = ty * yv, h4 = tx * yv;      \
      _Pragma("unroll") for (int k = 1; k < 11; ++k) {                       \
        xv = xl[rr][k]; yv = yl[rr][k];                                      \
        tx = w[k] * xv; ty = w[k] * yv;                                      \
        h0 += tx; h1 += ty;                                                  \
        h2 = fmaf(tx, xv, h2);                                               \
        h3 = fmaf(ty, yv, h3);                                               \
        h4 = fmaf(tx, yv, h4);                                               \
      }                                                                      \
      hist[(2 * (P) + rr) % 12][0] = h0;                                     \
      hist[(2 * (P) + rr) % 12][1] = h1;                                     \
      hist[(2 * (P) + rr) % 12][2] = h2;                                     \
      hist[(2 * (P) + rr) % 12][3] = h3;                                     \
      hist[(2 * (P) + rr) % 12][4] = h4;                                     \
    }                                                                        \
    ri += 2;                                                                 \
    LOADROWS(ri);                                                            \
    if (DO_OUT) {                                                            \
      _Pragma("unroll") for (int rr2 = 0; rr2 < 2; ++rr2) {                  \
        const int sb = 2 * (P) + 2 + rr2;                                    \
        float m1 = w[0] * hist[(sb) % 12][0];                                \
        float m2 = w[0] * hist[(sb) % 12][1];                                \
        float vxx = w[0] * hist[(sb) % 12][2];                               \
        float vyy = w[0] * hist[(sb) % 12][3];                               \
        float vxy = w[0] * hist[(sb) % 12][4];                               \
        _Pragma("unroll") for (int k = 1; k < 11; ++k) {                     \
          m1 = fmaf(w[k], hist[(sb + k) % 12][0], m1);                       \
          m2 = fmaf(w[k], hist[(sb + k) % 12][1], m2);                       \
          vxx = fmaf(w[k], hist[(sb + k) % 12][2], vxx);                     \
          vyy = fmaf(w[k], hist[(sb + k) % 12][3], vyy);                     \
          vxy = fmaf(w[k], hist[(sb + k) % 12][4], vxy);                     \
        }                                                                    \
        float mu12 = m1 * m2;                                                \
        float m1s = m1 * m1, m2s = m2 * m2;                                  \
        float s12 = vxy - mu12;                                              \
        float num = fmaf(2.f, mu12, C1c) * fmaf(2.f, s12, C2c);              \
        float msum = m1s + m2s;                                              \
        float den = (msum + C1c) * ((vxx + vyy) - msum + C2c);               \
        float r = __builtin_amdgcn_rcpf(den);                                \
        r = r * fmaf(-den, r, 2.0f);                                         \
        ssim_acc = fmaf(num, r, ssim_acc);                                   \
      }                                                                      \
    }                                                                        \
  } while (0)

__global__ __launch_bounds__(256, 3) void ssim_fused(
    const float* __restrict__ X, const float* __restrict__ Y,
    double* __restrict__ ws) {
  const int t = threadIdx.x;
  const int cb = blockIdx.x & 1;              // column half (0: 0-255, 1: 256-511)
  const int r0 = (blockIdx.x >> 1) << 6;      // row strip base (8 strips of 64)
  const int c0 = (cb << 8) + t;               // owned column
  const size_t ib = (size_t)blockIdx.y << 18; // image plane (192 planes)
  const float* __restrict__ xi = X + ib;
  const float* __restrict__ yi = Y + ib;

  // Gaussian weights, f32 like the reference; hoisted to SGPRs via
  // readfirstlane (wave-uniform) so FMAs use scalar operands.
  float w[11];
  {
    float wr[11], s = 0.f;
#pragma unroll
    for (int i = 0; i < 11; ++i) {
      float d = (float)(i - 5);
      wr[i] = expf(-d * d * (1.0f / 4.5f));
      s += wr[i];
    }
    float inv = 1.0f / s;
#pragma unroll
    for (int i = 0; i < 11; ++i) w[i] = rfl(wr[i] * inv);
  }

  // wave-uniform border flag: waves covering cols 0-63 or 448-511
  const bool bw = ((c0 >> 6) == 0) || ((c0 >> 6) == 7);

  float hist[12][5];     // circular hconv history: [row slot][signal]
  float xl[2][12], yl[2][12];
  float ssim_acc = 0.f, mse_acc = 0.f;
  int ri = r0 - 5;

  LOADROWS(ri);          // rows r0-5, r0-4
  ITER(0, false); ITER(1, false); ITER(2, false); ITER(3, false); ITER(4, false);
  ITER(5, true);
#pragma unroll 1
  for (int g = 0; g < 5; ++g) {   // n = 6 .. 35
    ITER(0, true); ITER(1, true); ITER(2, true);
    ITER(3, true); ITER(4, true); ITER(5, true);
  }
  ITER(0, true);                  // n = 36

  // reduction: wave shuffle -> LDS -> one f64 atomic pair per block
#pragma unroll
  for (int off = 32; off; off >>= 1) {
    ssim_acc += __shfl_down(ssim_acc, off);
    mse_acc += __shfl_down(mse_acc, off);
  }
  __shared__ float red[8];
  const int wv = t >> 6;
  if ((t & 63) == 0) { red[wv] = ssim_acc; red[4 + wv] = mse_acc; }
  __syncthreads();
  if (t == 0) {
    atomicAdd(ws, (double)(red[0] + red[1] + red[2] + red[3]));
    atomicAdd(ws + 1, (double)(red[4] + red[5] + red[6] + red[7]));
  }
}

__global__ void finalize_kernel(const double* __restrict__ ws,
                                float* __restrict__ out) {
  if (threadIdx.x == 0) {
    const double N = 50331648.0;  // 64*3*512*512
    double ssim = ws[0] / N;
    double mse = ws[1] / N;
    out[0] = (float)(0.7 * mse + 0.3 * (1.0 - ssim));
  }
}

extern "C" void kernel_launch(void* const* d_in, const int* in_sizes, int n_in,
                              void* d_out, int out_size, void* d_ws, size_t ws_size,
                              hipStream_t stream) {
  const float* recon = (const float*)d_in[0];
  const float* orig = (const float*)d_in[1];
  double* ws = (double*)d_ws;
  float* out = (float*)d_out;

  hipLaunchKernelGGL(zero_ws, dim3(1), dim3(64), 0, stream, ws);
  hipLaunchKernelGGL(ssim_fused, dim3(16, 192), dim3(256), 0, stream,
                     recon, orig, ws);
  hipLaunchKernelGGL(finalize_kernel, dim3(1), dim3(64), 0, stream, ws, out);
}